// Round 5
// baseline (229.709 us; speedup 1.0000x reference)
//
#include <hip/hip_runtime.h>
#include <hip/hip_bf16.h>

constexpr int B = 256, S = 1024, T = 64;
constexpr float LOG2E = 1.4426950408889634f;
constexpr float LN2   = 0.6931471805599453f;

typedef _Float16 h2 __attribute__((ext_vector_type(2)));

// d = dot(a_half2, b_half2) + c via fdot2 (f32 accumulate); a passed as raw bits
static __device__ __forceinline__ float dot2f(unsigned int abits, h2 b, float c) {
    return __builtin_amdgcn_fdot2(__builtin_bit_cast(h2, abits), b, c, false);
}

// One wave per chain. Lane j owns tag j. State p_j ~ exp(alpha_j - ln2*C).
__global__ __launch_bounds__(64, 1) void crf_fwd(
        const float* __restrict__ emis, const int* __restrict__ tags,
        const float* __restrict__ U,    const float* __restrict__ bs,
        const float* __restrict__ be,   float* __restrict__ nll) {
    __shared__ __align__(16) _Float16 qsh[T];   // 128 B: the broadcast buffer
    const int b = blockIdx.x;
    const int j = threadIdx.x;
    const float* eb = emis + (size_t)b * (S * T);
    const int*   tb = tags + (size_t)b * S;
    const float  bej = be[j];

    // W columns as f16 pairs: Wch[m] = (e^{U[2m][j]}, e^{U[2m+1][j]}), m=0..31
    h2 Wch[32];
#pragma unroll
    for (int m = 0; m < 32; ++m) {
        float w0 = __builtin_amdgcn_exp2f(U[(2 * m)     * T + j] * LOG2E);
        float w1 = __builtin_amdgcn_exp2f(U[(2 * m + 1) * T + j] * LOG2E);
        Wch[m] = h2{(_Float16)w0, (_Float16)w1};
    }

    // ---- path energy (exact, f32) ----
    float pe = 0.f;
#pragma unroll
    for (int sc = 0; sc < S / 64; ++sc) {
        int s  = sc * 64 + j;
        int tg = tb[s];
        float e = eb[s * T + tg];
        if (s == 0)     e += bs[tg];
        if (s == S - 1) e += be[tg];
        pe += e;
        if (s < S - 1)  pe += U[tg * T + tb[s + 1]];
    }
#pragma unroll
    for (int m = 1; m < 64; m <<= 1) pe += __shfl_xor(pe, m, 64);

    // ---- init: p = 2^{a0 - M0}, running log2-offset C = c2i + c2f ----
    float a0 = (eb[j] + bs[j]) * LOG2E;
    float M0 = a0;
#pragma unroll
    for (int m = 1; m < 64; m <<= 1) M0 = fmaxf(M0, __shfl_xor(M0, m, 64));
    float p   = __builtin_amdgcn_exp2f(a0 - M0);
    int   c2i = 0;
    const float c2f = M0;

    // one step: broadcast q via LDS, s_j = sum_i q_i W_ij, power-of-2 renorm, *e^x
    auto step = [&](float xval) {
        float ex = __builtin_amdgcn_exp2f(xval * LOG2E);   // off critical chain
        qsh[j] = (_Float16)p;                              // 1 cvt + 1 ds_write_b16
        __syncthreads();                                   // write visible
        uint4 qv[8];
#pragma unroll
        for (int g = 0; g < 8; ++g) qv[g] = ((const uint4*)qsh)[g];  // 8x ds_read_b128, broadcast
        __syncthreads();                                   // reads drained before next overwrite
        float s0 = 0.f, s1 = 0.f, s2 = 0.f, s3 = 0.f;
#pragma unroll
        for (int g = 0; g < 8; ++g) {
            s0 = dot2f(qv[g].x, Wch[4 * g + 0], s0);
            s1 = dot2f(qv[g].y, Wch[4 * g + 1], s1);
            s2 = dot2f(qv[g].z, Wch[4 * g + 2], s2);
            s3 = dot2f(qv[g].w, Wch[4 * g + 3], s3);
        }
        float ss = (s0 + s1) + (s2 + s3);
        // power-of-2 renorm anchored on lane 0 (cross-lane spread of ss <= 1.56x)
        unsigned int sb = __builtin_amdgcn_readfirstlane(__float_as_uint(ss));
        int ebits = (int)((sb >> 23) & 0xFF);
        float scale = __uint_as_float((unsigned int)(254 - ebits) << 23);
        c2i += ebits - 127;
        p = ss * scale * ex;
    };

    // ---- recursion t = 1..1023 with 8-deep ping-pong prefetch ----
    float xa[8], xb[8];
#pragma unroll
    for (int u = 0; u < 8; ++u) xa[u] = eb[(1 + u) * T + j];

    int t0 = 1;
    for (int k = 0; k < 63; ++k) {                 // 63 x 16 steps: t = 1..1008
#pragma unroll
        for (int u = 0; u < 8; ++u) xb[u] = eb[(t0 + 8 + u) * T + j];
#pragma unroll
        for (int u = 0; u < 8; ++u) step(xa[u]);   // t0 .. t0+7
#pragma unroll
        for (int u = 0; u < 8; ++u) xa[u] = eb[(t0 + 16 + u) * T + j];
#pragma unroll
        for (int u = 0; u < 8; ++u) step(xb[u]);   // t0+8 .. t0+15
        t0 += 16;
    }
    // t0 = 1009; xa holds x for t = 1009..1016
#pragma unroll
    for (int u = 0; u < 8; ++u) {
        int tt = t0 + 8 + u; if (tt > S - 1) tt = S - 1;  // t = 1017..1023 (clamped)
        xb[u] = eb[tt * T + j];
    }
#pragma unroll
    for (int u = 0; u < 8; ++u) step(xa[u]);       // t = 1009..1016
#pragma unroll
    for (int u = 0; u < 6; ++u) step(xb[u]);       // t = 1017..1022
    step(xb[6] + bej);                              // t = 1023 (+ b_end)

    // ---- free energy ----
    float sp = p;
#pragma unroll
    for (int m = 1; m < 64; m <<= 1) sp += __shfl_xor(sp, m, 64);
    float free_e = LN2 * (__builtin_amdgcn_logf(sp) + (float)c2i + c2f);

    if (j == 0) nll[b] = free_e - pe;
}

__global__ __launch_bounds__(256, 1) void crf_reduce(const float* __restrict__ nll,
                                                     float* __restrict__ out) {
    float v = nll[threadIdx.x];
#pragma unroll
    for (int m = 1; m < 64; m <<= 1) v += __shfl_xor(v, m, 64);
    __shared__ float acc[4];
    if ((threadIdx.x & 63) == 0) acc[threadIdx.x >> 6] = v;
    __syncthreads();
    if (threadIdx.x == 0) out[0] = (acc[0] + acc[1] + acc[2] + acc[3]) * (1.0f / B);
}

extern "C" void kernel_launch(void* const* d_in, const int* in_sizes, int n_in,
                              void* d_out, int out_size, void* d_ws, size_t ws_size,
                              hipStream_t stream) {
    const float* emis = (const float*)d_in[0];
    const int*   tags = (const int*)d_in[1];
    const float* U    = (const float*)d_in[2];
    const float* bs   = (const float*)d_in[3];
    const float* be   = (const float*)d_in[4];
    float* nll = (float*)d_ws;

    crf_fwd<<<dim3(B), dim3(64), 0, stream>>>(emis, tags, U, bs, be, nll);
    crf_reduce<<<dim3(1), dim3(256), 0, stream>>>(nll, (float*)d_out);
}

// Round 6
// 160.416 us; speedup vs baseline: 1.4320x; 1.4320x over previous
//
#include <hip/hip_runtime.h>
#include <hip/hip_bf16.h>

constexpr int B = 256, S = 1024, T = 64;
constexpr float LOG2E = 1.4426950408889634f;
constexpr float LN2   = 0.6931471805599453f;

typedef _Float16 h2 __attribute__((ext_vector_type(2)));

static __device__ __forceinline__ float dot2f(unsigned int abits, h2 b, float c) {
    return __builtin_amdgcn_fdot2(__builtin_bit_cast(h2, abits), b, c, false);
}
static __device__ __forceinline__ unsigned int pack2(float lo, float hi) {
    return __builtin_bit_cast(unsigned int, __builtin_amdgcn_cvt_pkrtz(lo, hi));
}
// value from lane^1 via DPP quad_perm(1,0,3,2) — VALU speed, no LDS pipe
static __device__ __forceinline__ float xor1_dpp(float x) {
    return __int_as_float(__builtin_amdgcn_update_dpp(
        __float_as_int(x), __float_as_int(x), 0xB1, 0xF, 0xF, true));
}

// Block = 2 waves per chain. Wave 0: forward t=0..511. Wave 1: backward t=1023..512.
// free_e = log(b_511^T a_511). Lane j owns tag j in both waves.
__global__ __launch_bounds__(128, 1) void crf_fwd(
        const float* __restrict__ emis, const int* __restrict__ tags,
        const float* __restrict__ U,    const float* __restrict__ bs,
        const float* __restrict__ be,   float* __restrict__ nll) {
    __shared__ float af[T], bfv[T], meta[4];
    const int bI  = blockIdx.x;
    const int tid = threadIdx.x;
    const int j    = tid & 63;
    const int wave = tid >> 6;
    const float* eb = emis + (size_t)bI * (S * T);
    const int*   tb = tags + (size_t)bI * S;
    const float  bej = be[j];

    // W fragments: fwd needs columns (s_j = sum_i q_i W_ij), bwd needs rows.
    h2 Wh[32];
#pragma unroll
    for (int m = 0; m < 32; ++m) {
        float w0, w1;
        if (wave == 0) {
            w0 = __builtin_amdgcn_exp2f(U[(2 * m)     * T + j] * LOG2E);
            w1 = __builtin_amdgcn_exp2f(U[(2 * m + 1) * T + j] * LOG2E);
        } else {
            w0 = __builtin_amdgcn_exp2f(U[j * T + 2 * m]     * LOG2E);
            w1 = __builtin_amdgcn_exp2f(U[j * T + 2 * m + 1] * LOG2E);
        }
        Wh[m] = __builtin_bit_cast(h2, pack2(w0, w1));
    }

    // ---- path energy: wave 0 covers s in [0,512), wave 1 covers [512,1024) ----
    float pe = 0.f;
#pragma unroll
    for (int c = 0; c < 8; ++c) {
        int s  = (wave * 8 + c) * 64 + j;
        int tg = tb[s];
        float e = eb[s * T + tg];
        if (s == 0)     e += bs[tg];
        if (s == S - 1) e += be[tg];
        pe += e;
        if (s < S - 1)  pe += U[tg * T + tb[s + 1]];
    }
#pragma unroll
    for (int m = 1; m < 64; m <<= 1) pe += __shfl_xor(pe, m, 64);

    // ---- state init ----
    float p, c2f;
    int   c2i = 0;
    if (wave == 0) {
        float a0 = (eb[j] + bs[j]) * LOG2E;
        float M0 = a0;
#pragma unroll
        for (int m = 1; m < 64; m <<= 1) M0 = fmaxf(M0, __shfl_xor(M0, m, 64));
        p = __builtin_amdgcn_exp2f(a0 - M0);
        c2f = M0;
    } else {
        p = 1.0f; c2f = 0.f;
    }

    // core matvec: given broadcast word source value v (pair-packed), dot + renorm
    auto matvec_renorm = [&](float v) -> float {
        float vh = xor1_dpp(v);
        unsigned int qb = pack2(v, vh);          // even lane 2i holds (v_2i, v_2i+1)
        float s0 = 0.f, s1 = 0.f, s2 = 0.f, s3 = 0.f;
#pragma unroll
        for (int i = 0; i < 32; i += 4) {
            s0 = dot2f(__builtin_amdgcn_readlane(qb, 2 * (i + 0)), Wh[i + 0], s0);
            s1 = dot2f(__builtin_amdgcn_readlane(qb, 2 * (i + 1)), Wh[i + 1], s1);
            s2 = dot2f(__builtin_amdgcn_readlane(qb, 2 * (i + 2)), Wh[i + 2], s2);
            s3 = dot2f(__builtin_amdgcn_readlane(qb, 2 * (i + 3)), Wh[i + 3], s3);
        }
        float ss = (s0 + s1) + (s2 + s3);
        unsigned int sb = __builtin_amdgcn_readfirstlane(__float_as_uint(ss));
        int ebits = (int)((sb >> 23) & 0xFF);
        c2i += ebits - 127;
        float scale = __uint_as_float((unsigned int)(254 - ebits) << 23);
        return ss * scale;
    };

    if (wave == 0) {
        // forward: p <- (W^T p) * e^{x_t}, t = 1..511  (N = 511 steps, x idx = 1+u)
        constexpr int N = 511;
        auto xld = [&](int u) { int uu = u < N ? u : N - 1; return eb[(1 + uu) * T + j]; };
        auto step = [&](float xval) {
            float ex = __builtin_amdgcn_exp2f(xval * LOG2E);
            p = matvec_renorm(p) * ex;
        };
        float xa[8], xb[8];
#pragma unroll
        for (int u = 0; u < 8; ++u) xa[u] = xld(u);
        int u0 = 0;
        while (u0 + 16 <= N) {
#pragma unroll
            for (int v = 0; v < 8; ++v) xb[v] = xld(u0 + 8 + v);
#pragma unroll
            for (int v = 0; v < 8; ++v) step(xa[v]);
#pragma unroll
            for (int v = 0; v < 8; ++v) xa[v] = xld(u0 + 16 + v);
#pragma unroll
            for (int v = 0; v < 8; ++v) step(xb[v]);
            u0 += 16;
        }
        if (u0 < N) {
#pragma unroll
            for (int v = 0; v < 8; ++v) xb[v] = xld(u0 + 8 + v);
#pragma unroll
            for (int v = 0; v < 8; ++v) if (u0 + v < N) step(xa[v]);
#pragma unroll
            for (int v = 0; v < 8; ++v) if (u0 + 8 + v < N) step(xb[v]);
        }
        af[j] = p;
        if (j == 0) { meta[0] = c2f + (float)c2i; meta[2] = pe; }
    } else {
        // backward: b <- W (b * e^{x_t}), t = 1023..512 (N = 512 steps, x idx = 1023-u)
        constexpr int N = 512;
        auto xld = [&](int u) { int uu = u < N ? u : N - 1; return eb[(1023 - uu) * T + j]; };
        auto step = [&](float xval) {
            float ex = __builtin_amdgcn_exp2f(xval * LOG2E);
            p = matvec_renorm(p * ex);
        };
        float xa[8], xb[8];
#pragma unroll
        for (int u = 0; u < 8; ++u) xa[u] = xld(u);
        xa[0] += bej;                       // x_1023 includes b_end
        int u0 = 0;
        while (u0 + 16 <= N) {
#pragma unroll
            for (int v = 0; v < 8; ++v) xb[v] = xld(u0 + 8 + v);
#pragma unroll
            for (int v = 0; v < 8; ++v) step(xa[v]);
#pragma unroll
            for (int v = 0; v < 8; ++v) xa[v] = xld(u0 + 16 + v);
#pragma unroll
            for (int v = 0; v < 8; ++v) step(xb[v]);
            u0 += 16;
        }
        if (u0 < N) {
#pragma unroll
            for (int v = 0; v < 8; ++v) xb[v] = xld(u0 + 8 + v);
#pragma unroll
            for (int v = 0; v < 8; ++v) if (u0 + v < N) step(xa[v]);
#pragma unroll
            for (int v = 0; v < 8; ++v) if (u0 + 8 + v < N) step(xb[v]);
        }
        bfv[j] = p;
        if (j == 0) { meta[1] = (float)c2i; meta[3] = pe; }
    }

    __syncthreads();
    if (tid < 64) {
        float v = af[j] * bfv[j];
#pragma unroll
        for (int m = 1; m < 64; m <<= 1) v += __shfl_xor(v, m, 64);
        if (j == 0) {
            float free_e = LN2 * (__builtin_amdgcn_logf(v) + meta[0] + meta[1]);
            nll[bI] = free_e - (meta[2] + meta[3]);
        }
    }
}

__global__ __launch_bounds__(256, 1) void crf_reduce(const float* __restrict__ nll,
                                                     float* __restrict__ out) {
    float v = nll[threadIdx.x];
#pragma unroll
    for (int m = 1; m < 64; m <<= 1) v += __shfl_xor(v, m, 64);
    __shared__ float acc[4];
    if ((threadIdx.x & 63) == 0) acc[threadIdx.x >> 6] = v;
    __syncthreads();
    if (threadIdx.x == 0) out[0] = (acc[0] + acc[1] + acc[2] + acc[3]) * (1.0f / B);
}

extern "C" void kernel_launch(void* const* d_in, const int* in_sizes, int n_in,
                              void* d_out, int out_size, void* d_ws, size_t ws_size,
                              hipStream_t stream) {
    const float* emis = (const float*)d_in[0];
    const int*   tags = (const int*)d_in[1];
    const float* U    = (const float*)d_in[2];
    const float* bs   = (const float*)d_in[3];
    const float* be   = (const float*)d_in[4];
    float* nll = (float*)d_ws;

    crf_fwd<<<dim3(B), dim3(128), 0, stream>>>(emis, tags, U, bs, be, nll);
    crf_reduce<<<dim3(1), dim3(256), 0, stream>>>(nll, (float*)d_out);
}